// Round 17
// baseline (1484.641 us; speedup 1.0000x reference)
//
#include <hip/hip_runtime.h>

#define BB 512
#define TT 1024
#define DD 64
#define HH 32
#define CC 4
#define TILE 16
#define NT (TT / TILE)

typedef float f4 __attribute__((ext_vector_type(4)));
typedef _Float16 hv2 __attribute__((ext_vector_type(2)));

#define LOG2E 1.4426950408889634f
#define TWO_LOG2E 2.8853900817779268f

__device__ __forceinline__ float rcpf(float x) { return __builtin_amdgcn_rcpf(x); }
__device__ __forceinline__ float ex2(float x) { return __builtin_amdgcn_exp2f(x); }
__device__ __forceinline__ float sigm2(float x) { return rcpf(1.0f + ex2(-x)); }
__device__ __forceinline__ float tanh2(float x) {
    return 1.0f - 2.0f * rcpf(ex2(x + x) + 1.0f);
}
__device__ __forceinline__ float tanh_c(float c) {
    return 1.0f - 2.0f * rcpf(ex2(c * TWO_LOG2E) + 1.0f);
}
__device__ __forceinline__ float pk2(float a, float b) {
    hv2 t; t.x = (_Float16)a; t.y = (_Float16)b;
    return __builtin_bit_cast(float, t);
}
__device__ __forceinline__ hv2 bch(float x) { return __builtin_bit_cast(hv2, x); }
__device__ __forceinline__ float fdot2(float w, float h, float c) {
    return __builtin_amdgcn_fdot2(bch(w), bch(h), c, false);
}

#define DOT32(a0, a1, a2, a3, W, H4)                    \
    _Pragma("unroll")                                   \
    for (int k2 = 0; k2 < 4; ++k2) {                    \
        f4 h_ = H4[k2];                                 \
        a0 = fdot2(W[4 * k2 + 0], h_.x, a0);            \
        a1 = fdot2(W[4 * k2 + 1], h_.y, a1);            \
        a2 = fdot2(W[4 * k2 + 2], h_.z, a2);            \
        a3 = fdot2(W[4 * k2 + 3], h_.w, a3);            \
    }

// gate combine via DS shuffle (R13-proven)
#define COMBINE(zA, zB, zi, zf, zg, zo)                 \
    {                                                   \
        float pA_ = __shfl_xor(zA, 32, 64);             \
        float pB_ = __shfl_xor(zB, 32, 64);             \
        zi = half ? pA_ : zA; zf = half ? zA : pA_;     \
        zg = half ? pB_ : zB; zo = half ? zB : pB_;     \
    }

#define GATHER4(dst, srcLDS)                            \
    _Pragma("unroll")                                   \
    for (int k2 = 0; k2 < 4; ++k2) dst[k2] = ((const f4*)(srcLDS))[k2];

// ---------------- Kernel 1: zx = (bias0 + w_ih0 . x) * log2e ----------------
__global__ void __launch_bounds__(128, 4)
zx_gemm(const float* __restrict__ states,  // [B,T,64]
        const float* __restrict__ w_ih0,   // [128,68]
        const float* __restrict__ b_ih0,
        const float* __restrict__ b_hh0,
        float* __restrict__ zx)            // [B,T,128] PRESCALED
{
    const int b = blockIdx.y;
    const int tile = blockIdx.x;
    const int tid = threadIdx.x;
    __shared__ __align__(16) float xs[16][DD];

    const int tbase = tile * 16;
#pragma unroll
    for (int i = 0; i < 2; ++i) {
        int f = i * 128 + tid;
        int row = f >> 4, c4 = f & 15;
        int t = tbase + row; if (t > TT - 1) t = TT - 1;
        ((f4*)xs)[f] = *(const f4*)(states + ((size_t)b * TT + t) * DD + c4 * 4);
    }
    __syncthreads();

    const int r = tid;
    const f4* wr = (const f4*)(w_ih0 + (size_t)r * 68);
    f4 w[16];
#pragma unroll
    for (int k = 0; k < 16; ++k) w[k] = wr[k];
    const float bias = b_ih0[r] + b_hh0[r];

    for (int i = 0; i < 16; ++i) {
        int t = tbase + i;
        if (t >= TT) break;
        const f4* xv = (const f4*)xs[i];
        float a0 = bias, a1 = 0.f, a2 = 0.f, a3 = 0.f;
#pragma unroll
        for (int k = 0; k < 16; ++k) {
            f4 x4 = xv[k];
            a0 = fmaf(w[k].x, x4.x, a0);
            a1 = fmaf(w[k].y, x4.y, a1);
            a2 = fmaf(w[k].z, x4.z, a2);
            a3 = fmaf(w[k].w, x4.w, a3);
        }
        zx[((size_t)b * TT + t) * 128 + r] = ((a0 + a1) + (a2 + a3)) * LOG2E;
    }
}

// ---------------- Kernel 2: DUAL-BATCH tile-staged exp2-domain recurrence ----------
// One wave runs TWO independent batch elements (b0, b1); their dependence
// chains interleave in the issue slots, hiding each other's DS/exp latency.
// Weights shared in registers; per-element state/LDS duplicated. Structure
// and numerics are R13 verbatim, duplicated.
__global__ void __launch_bounds__(64, 1)
lstm_pipe2(const float* __restrict__ zx,      // [B,TT,128] prescaled
           const float* __restrict__ taup,
           const float* __restrict__ gumbel,  // [T,B,1,C]
           const float* __restrict__ w_ih0,   // [128,68] (ct cols 64..67)
           const float* __restrict__ w_hh0,   // [128,32]
           const float* __restrict__ w_ih1,   // [128,32]
           const float* __restrict__ w_hh1,   // [128,32]
           const float* __restrict__ b_ih1,
           const float* __restrict__ b_hh1,
           const float* __restrict__ w_lin,   // [4,32]
           const float* __restrict__ b_lin,   // [4]
           float* __restrict__ out)           // [B,T,4]
{
    const int b0   = 2 * (int)blockIdx.x;
    const int b1   = b0 + 1;
    const int l    = threadIdx.x;     // 0..63
    const int half = l >> 5;
    const int rA   = l;               // rows l (i|f) and l+64 (g|o)
    const int rB   = l + 64;
    const int c    = l >> 4;          // q channel group

    __shared__ __align__(16) float zbufs[2][2][TILE][128];   // [elem][dbuf] 32 KB
    __shared__ __align__(16) float4 gbufs[2][2][TILE];       // pre-scaled gumbel
    __shared__ __align__(16) _Float16 h1hs[2][HH];
    __shared__ __align__(16) _Float16 h2hs[2][HH];

    const float inv_tau = rcpf(taup[0]);
    const float gs = LOG2E * inv_tau;

    // ---- shared weights: wct f32*log2e; recurrent f16-pairs *log2e; wlc *gs ----
    f4 wctA = *(const f4*)(w_ih0 + (size_t)rA * 68 + 64);
    f4 wctB = *(const f4*)(w_ih0 + (size_t)rB * 68 + 64);
    wctA *= LOG2E; wctB *= LOG2E;
    float wh0A[16], wh0B[16], wi1A[16], wi1B[16], wh1A[16], wh1B[16], wlc[16];
#pragma unroll
    for (int k = 0; k < 8; ++k) {
        f4 w;
        w = *(const f4*)(w_hh0 + (size_t)rA * HH + 4 * k) * LOG2E;
        wh0A[2 * k] = pk2(w.x, w.y); wh0A[2 * k + 1] = pk2(w.z, w.w);
        w = *(const f4*)(w_hh0 + (size_t)rB * HH + 4 * k) * LOG2E;
        wh0B[2 * k] = pk2(w.x, w.y); wh0B[2 * k + 1] = pk2(w.z, w.w);
        w = *(const f4*)(w_ih1 + (size_t)rA * HH + 4 * k) * LOG2E;
        wi1A[2 * k] = pk2(w.x, w.y); wi1A[2 * k + 1] = pk2(w.z, w.w);
        w = *(const f4*)(w_ih1 + (size_t)rB * HH + 4 * k) * LOG2E;
        wi1B[2 * k] = pk2(w.x, w.y); wi1B[2 * k + 1] = pk2(w.z, w.w);
        w = *(const f4*)(w_hh1 + (size_t)rA * HH + 4 * k) * LOG2E;
        wh1A[2 * k] = pk2(w.x, w.y); wh1A[2 * k + 1] = pk2(w.z, w.w);
        w = *(const f4*)(w_hh1 + (size_t)rB * HH + 4 * k) * LOG2E;
        wh1B[2 * k] = pk2(w.x, w.y); wh1B[2 * k + 1] = pk2(w.z, w.w);
        w = *(const f4*)(w_lin + (size_t)c * HH + 4 * k) * gs;
        wlc[2 * k] = pk2(w.x, w.y); wlc[2 * k + 1] = pk2(w.z, w.w);
    }
    const float bias1A = (b_ih1[rA] + b_hh1[rA]) * LOG2E;
    const float bias1B = (b_ih1[rB] + b_hh1[rB]) * LOG2E;
    const float blc = b_lin[c] * gs;

    const float* __restrict__ zb0 = zx + (size_t)b0 * TT * 128;
    const float* __restrict__ zb1 = zx + (size_t)b1 * TT * 128;
    float* __restrict__ ob0 = out + (size_t)b0 * TT * CC;
    float* __restrict__ ob1 = out + (size_t)b1 * TT * CC;
    const int srow = l >> 5;          // staging: f4 slot f=i*64+l -> row i*2+srow, col4 l&31
    const int scol = l & 31;

    // ---- stage tile 0 for both elements: zx rows 1..16, gumbel t=0..15 ----
    {
        f4 sz0[8], sz1[8];
#pragma unroll
        for (int i = 0; i < 8; ++i) {
            int row = 1 + i * 2 + srow;
            sz0[i] = *(const f4*)(zb0 + (size_t)row * 128 + scol * 4);
            sz1[i] = *(const f4*)(zb1 + (size_t)row * 128 + scol * 4);
        }
        float4 gv0 = *(const float4*)(gumbel + ((size_t)(l & 15) * BB + b0) * CC);
        float4 gv1 = *(const float4*)(gumbel + ((size_t)(l & 15) * BB + b1) * CC);
        gv0.x *= gs; gv0.y *= gs; gv0.z *= gs; gv0.w *= gs;
        gv1.x *= gs; gv1.y *= gs; gv1.z *= gs; gv1.w *= gs;
#pragma unroll
        for (int i = 0; i < 8; ++i) {
            ((f4*)&zbufs[0][0][0][0])[i * 64 + l] = sz0[i];
            ((f4*)&zbufs[1][0][0][0])[i * 64 + l] = sz1[i];
        }
        if (l < 16) { gbufs[0][0][l] = gv0; gbufs[1][0][l] = gv1; }
    }

    float cs10 = 0.f, cs20 = 0.f, cs11 = 0.f, cs21 = 0.f;
    f4 h1g0[4], h1g1[4];

    // ---- prologue: h1(0), h2(0) for both; ct0 = one-hot(0) ----
    {
        float zA = zb0[rA] + wctA.x;
        float zB = zb0[rB] + wctB.x;
        float zi, zf, zg, zo;
        COMBINE(zA, zB, zi, zf, zg, zo);
        (void)zf;
        cs10 = sigm2(zi) * tanh2(zg);
        float h1n = sigm2(zo) * tanh_c(cs10);
        if (l < HH) h1hs[0][l] = (_Float16)h1n;
        GATHER4(h1g0, h1hs[0]);
        float bA0 = bias1A, bA1 = 0.f, bA2 = 0.f, bA3 = 0.f;
        float bB0 = bias1B, bB1 = 0.f, bB2 = 0.f, bB3 = 0.f;
        DOT32(bA0, bA1, bA2, bA3, wi1A, h1g0);
        DOT32(bB0, bB1, bB2, bB3, wi1B, h1g0);
        zA = (bA0 + bA1) + (bA2 + bA3);
        zB = (bB0 + bB1) + (bB2 + bB3);
        COMBINE(zA, zB, zi, zf, zg, zo);
        cs20 = sigm2(zi) * tanh2(zg);
        float h2n = sigm2(zo) * tanh_c(cs20);
        if (l < HH) h2hs[0][l] = (_Float16)h2n;
    }
    {
        float zA = zb1[rA] + wctA.x;
        float zB = zb1[rB] + wctB.x;
        float zi, zf, zg, zo;
        COMBINE(zA, zB, zi, zf, zg, zo);
        (void)zf;
        cs11 = sigm2(zi) * tanh2(zg);
        float h1n = sigm2(zo) * tanh_c(cs11);
        if (l < HH) h1hs[1][l] = (_Float16)h1n;
        GATHER4(h1g1, h1hs[1]);
        float bA0 = bias1A, bA1 = 0.f, bA2 = 0.f, bA3 = 0.f;
        float bB0 = bias1B, bB1 = 0.f, bB2 = 0.f, bB3 = 0.f;
        DOT32(bA0, bA1, bA2, bA3, wi1A, h1g1);
        DOT32(bB0, bB1, bB2, bB3, wi1B, h1g1);
        zA = (bA0 + bA1) + (bA2 + bA3);
        zB = (bB0 + bB1) + (bB2 + bB3);
        COMBINE(zA, zB, zi, zf, zg, zo);
        cs21 = sigm2(zi) * tanh2(zg);
        float h2n = sigm2(zo) * tanh_c(cs21);
        if (l < HH) h2hs[1][l] = (_Float16)h2n;
    }

    // ---- main loop: tiles of 16 steps, staging split in 8-step halves ----
    for (int k = 0; k < NT; ++k) {
        const int cb = k & 1, nb = cb ^ 1;
        const int kn = (k + 1 < NT) ? k + 1 : 0;
        float4 gv0, gv1;

#pragma unroll
        for (int hf = 0; hf < 2; ++hf) {
            f4 szh0[4], szh1[4];
#pragma unroll
            for (int i = 0; i < 4; ++i) {
                int ii = hf * 4 + i;
                int row = kn * TILE + 1 + ii * 2 + srow;
                if (row > TT - 1) row = TT - 1;
                szh0[i] = *(const f4*)(zb0 + (size_t)row * 128 + scol * 4);
                szh1[i] = *(const f4*)(zb1 + (size_t)row * 128 + scol * 4);
            }
            if (hf == 0) {
                gv0 = *(const float4*)(gumbel +
                        ((size_t)(kn * TILE + (l & 15)) * BB + b0) * CC);
                gv1 = *(const float4*)(gumbel +
                        ((size_t)(kn * TILE + (l & 15)) * BB + b1) * CC);
            }

#pragma unroll 1
            for (int s8 = 0; s8 < 8; ++s8) {
                const int s = hf * 8 + s8;
                const int t = k * TILE + s;

                // (1) both elements: zx(t+1), gumbel(t), h2(t) gathers
                const float zxnA0 = zbufs[0][cb][s][rA];
                const float zxnB0 = zbufs[0][cb][s][rB];
                const float zxnA1 = zbufs[1][cb][s][rA];
                const float zxnB1 = zbufs[1][cb][s][rB];
                const float4 gtc0 = gbufs[0][cb][s];
                const float4 gtc1 = gbufs[1][cb][s];
                f4 h2g0[4], h2g1[4];
                GATHER4(h2g0, h2hs[0]);
                GATHER4(h2g1, h2hs[1]);

                // (2) L0(t+1) main dots: wh0 . h1(t), both
                float aA00 = 0.f, aA10 = 0.f, aA20 = 0.f, aA30 = 0.f;
                float aB00 = 0.f, aB10 = 0.f, aB20 = 0.f, aB30 = 0.f;
                float aA01 = 0.f, aA11 = 0.f, aA21 = 0.f, aA31 = 0.f;
                float aB01 = 0.f, aB11 = 0.f, aB21 = 0.f, aB31 = 0.f;
                DOT32(aA00, aA10, aA20, aA30, wh0A, h1g0);
                DOT32(aA01, aA11, aA21, aA31, wh0A, h1g1);
                DOT32(aB00, aB10, aB20, aB30, wh0B, h1g0);
                DOT32(aB01, aB11, aB21, aB31, wh0B, h1g1);

                // (3) q dots, both
                float s00 = blc, s10 = 0.f, s20 = 0.f, s30 = 0.f;
                float s01 = blc, s11 = 0.f, s21 = 0.f, s31 = 0.f;
                DOT32(s00, s10, s20, s30, wlc, h2g0);
                DOT32(s01, s11, s21, s31, wlc, h2g1);
                float qown0 = (s00 + s10) + (s20 + s30);
                float qown1 = (s01 + s11) + (s21 + s31);

                // (4) q perms + exp2 softmax, both
                float t1_0 = __shfl_xor(qown0, 16, 64);
                float t1_1 = __shfl_xor(qown1, 16, 64);
                float t2_0 = __shfl_xor(qown0, 32, 64);
                float t2_1 = __shfl_xor(qown1, 32, 64);
                float t3_0 = __shfl_xor(t1_0, 32, 64);
                float t3_1 = __shfl_xor(t1_1, 32, 64);
                float q00 = (c == 0) ? qown0 : (c == 1) ? t1_0 : (c == 2) ? t2_0 : t3_0;
                float q10 = (c == 0) ? t1_0 : (c == 1) ? qown0 : (c == 2) ? t3_0 : t2_0;
                float q20 = (c == 0) ? t2_0 : (c == 1) ? t3_0 : (c == 2) ? qown0 : t1_0;
                float q30 = (c == 0) ? t3_0 : (c == 1) ? t2_0 : (c == 2) ? t1_0 : qown0;
                float q01 = (c == 0) ? qown1 : (c == 1) ? t1_1 : (c == 2) ? t2_1 : t3_1;
                float q11 = (c == 0) ? t1_1 : (c == 1) ? qown1 : (c == 2) ? t3_1 : t2_1;
                float q21 = (c == 0) ? t2_1 : (c == 1) ? t3_1 : (c == 2) ? qown1 : t1_1;
                float q31 = (c == 0) ? t3_1 : (c == 1) ? t2_1 : (c == 2) ? t1_1 : qown1;
                float e00 = ex2(q00 + gtc0.x), e10 = ex2(q10 + gtc0.y);
                float e20 = ex2(q20 + gtc0.z), e30 = ex2(q30 + gtc0.w);
                float e01 = ex2(q01 + gtc1.x), e11 = ex2(q11 + gtc1.y);
                float e21 = ex2(q21 + gtc1.z), e31 = ex2(q31 + gtc1.w);
                float inv0 = rcpf((e00 + e10) + (e20 + e30));
                float inv1 = rcpf((e01 + e11) + (e21 + e31));
                if (l == 0) {
                    *(float4*)(ob0 + (size_t)t * CC) =
                        make_float4(e00 * inv0, e10 * inv0, e20 * inv0, e30 * inv0);
                    *(float4*)(ob1 + (size_t)t * CC) =
                        make_float4(e01 * inv1, e11 * inv1, e21 * inv1, e31 * inv1);
                }

                // (5) L0 tails + combine + act -> h1(t+1), both
                {
                    float weA0 = wctA.x * e00, weA1 = wctA.y * e10;
                    float weA2 = wctA.z * e20, weA3 = wctA.w * e30;
                    float weB0 = wctB.x * e00, weB1 = wctB.y * e10;
                    float weB2 = wctB.z * e20, weB3 = wctB.w * e30;
                    aA00 = fmaf(weA0, inv0, aA00 + zxnA0); aA10 = fmaf(weA1, inv0, aA10);
                    aA20 = fmaf(weA2, inv0, aA20);         aA30 = fmaf(weA3, inv0, aA30);
                    aB00 = fmaf(weB0, inv0, aB00 + zxnB0); aB10 = fmaf(weB1, inv0, aB10);
                    aB20 = fmaf(weB2, inv0, aB20);         aB30 = fmaf(weB3, inv0, aB30);
                    float zA = (aA00 + aA10) + (aA20 + aA30);
                    float zB = (aB00 + aB10) + (aB20 + aB30);
                    float zi, zf, zg, zo;
                    COMBINE(zA, zB, zi, zf, zg, zo);
                    cs10 = fmaf(sigm2(zf), cs10, sigm2(zi) * tanh2(zg));
                    float h1n = sigm2(zo) * tanh_c(cs10);
                    if (l < HH) h1hs[0][l] = (_Float16)h1n;
                }
                {
                    float weA0 = wctA.x * e01, weA1 = wctA.y * e11;
                    float weA2 = wctA.z * e21, weA3 = wctA.w * e31;
                    float weB0 = wctB.x * e01, weB1 = wctB.y * e11;
                    float weB2 = wctB.z * e21, weB3 = wctB.w * e31;
                    aA01 = fmaf(weA0, inv1, aA01 + zxnA1); aA11 = fmaf(weA1, inv1, aA11);
                    aA21 = fmaf(weA2, inv1, aA21);         aA31 = fmaf(weA3, inv1, aA31);
                    aB01 = fmaf(weB0, inv1, aB01 + zxnB1); aB11 = fmaf(weB1, inv1, aB11);
                    aB21 = fmaf(weB2, inv1, aB21);         aB31 = fmaf(weB3, inv1, aB31);
                    float zA = (aA01 + aA11) + (aA21 + aA31);
                    float zB = (aB01 + aB11) + (aB21 + aB31);
                    float zi, zf, zg, zo;
                    COMBINE(zA, zB, zi, zf, zg, zo);
                    cs11 = fmaf(sigm2(zf), cs11, sigm2(zi) * tanh2(zg));
                    float h1n = sigm2(zo) * tanh_c(cs11);
                    if (l < HH) h1hs[1][l] = (_Float16)h1n;
                }

                // (6) h1(t+1) gathers, both
                GATHER4(h1g0, h1hs[0]);
                GATHER4(h1g1, h1hs[1]);

                // (7) L1(t+1): wh1 . h2(t) then wi1 . h1(t+1), both
                {
                    float bA0 = bias1A, bA1 = 0.f, bA2 = 0.f, bA3 = 0.f;
                    float bB0 = bias1B, bB1 = 0.f, bB2 = 0.f, bB3 = 0.f;
                    DOT32(bA0, bA1, bA2, bA3, wh1A, h2g0);
                    DOT32(bB0, bB1, bB2, bB3, wh1B, h2g0);
                    DOT32(bA0, bA1, bA2, bA3, wi1A, h1g0);
                    DOT32(bB0, bB1, bB2, bB3, wi1B, h1g0);
                    float zA = (bA0 + bA1) + (bA2 + bA3);
                    float zB = (bB0 + bB1) + (bB2 + bB3);
                    float zi, zf, zg, zo;
                    COMBINE(zA, zB, zi, zf, zg, zo);
                    cs20 = fmaf(sigm2(zf), cs20, sigm2(zi) * tanh2(zg));
                    float h2n = sigm2(zo) * tanh_c(cs20);
                    if (l < HH) h2hs[0][l] = (_Float16)h2n;
                }
                {
                    float bA0 = bias1A, bA1 = 0.f, bA2 = 0.f, bA3 = 0.f;
                    float bB0 = bias1B, bB1 = 0.f, bB2 = 0.f, bB3 = 0.f;
                    DOT32(bA0, bA1, bA2, bA3, wh1A, h2g1);
                    DOT32(bB0, bB1, bB2, bB3, wh1B, h2g1);
                    DOT32(bA0, bA1, bA2, bA3, wi1A, h1g1);
                    DOT32(bB0, bB1, bB2, bB3, wi1B, h1g1);
                    float zA = (bA0 + bA1) + (bA2 + bA3);
                    float zB = (bB0 + bB1) + (bB2 + bB3);
                    float zi, zf, zg, zo;
                    COMBINE(zA, zB, zi, zf, zg, zo);
                    cs21 = fmaf(sigm2(zf), cs21, sigm2(zi) * tanh2(zg));
                    float h2n = sigm2(zo) * tanh_c(cs21);
                    if (l < HH) h2hs[1][l] = (_Float16)h2n;
                }
            }

            // commit staged rows (>=8 steps of vmcnt slack)
#pragma unroll
            for (int i = 0; i < 4; ++i) {
                ((f4*)&zbufs[0][nb][0][0])[(hf * 4 + i) * 64 + l] = szh0[i];
                ((f4*)&zbufs[1][nb][0][0])[(hf * 4 + i) * 64 + l] = szh1[i];
            }
        }
        gv0.x *= gs; gv0.y *= gs; gv0.z *= gs; gv0.w *= gs;
        gv1.x *= gs; gv1.y *= gs; gv1.z *= gs; gv1.w *= gs;
        if (l < 16) { gbufs[0][nb][l] = gv0; gbufs[1][nb][l] = gv1; }

        // ---- weight pins ONCE PER TILE ----
        asm volatile("" : "+v"(wh0A[0]), "+v"(wh0A[1]), "+v"(wh0A[2]), "+v"(wh0A[3]),
                          "+v"(wh0A[4]), "+v"(wh0A[5]), "+v"(wh0A[6]), "+v"(wh0A[7]),
                          "+v"(wh0A[8]), "+v"(wh0A[9]), "+v"(wh0A[10]), "+v"(wh0A[11]),
                          "+v"(wh0A[12]), "+v"(wh0A[13]), "+v"(wh0A[14]), "+v"(wh0A[15]));
        asm volatile("" : "+v"(wh0B[0]), "+v"(wh0B[1]), "+v"(wh0B[2]), "+v"(wh0B[3]),
                          "+v"(wh0B[4]), "+v"(wh0B[5]), "+v"(wh0B[6]), "+v"(wh0B[7]),
                          "+v"(wh0B[8]), "+v"(wh0B[9]), "+v"(wh0B[10]), "+v"(wh0B[11]),
                          "+v"(wh0B[12]), "+v"(wh0B[13]), "+v"(wh0B[14]), "+v"(wh0B[15]));
        asm volatile("" : "+v"(wi1A[0]), "+v"(wi1A[1]), "+v"(wi1A[2]), "+v"(wi1A[3]),
                          "+v"(wi1A[4]), "+v"(wi1A[5]), "+v"(wi1A[6]), "+v"(wi1A[7]),
                          "+v"(wi1A[8]), "+v"(wi1A[9]), "+v"(wi1A[10]), "+v"(wi1A[11]),
                          "+v"(wi1A[12]), "+v"(wi1A[13]), "+v"(wi1A[14]), "+v"(wi1A[15]));
        asm volatile("" : "+v"(wi1B[0]), "+v"(wi1B[1]), "+v"(wi1B[2]), "+v"(wi1B[3]),
                          "+v"(wi1B[4]), "+v"(wi1B[5]), "+v"(wi1B[6]), "+v"(wi1B[7]),
                          "+v"(wi1B[8]), "+v"(wi1B[9]), "+v"(wi1B[10]), "+v"(wi1B[11]),
                          "+v"(wi1B[12]), "+v"(wi1B[13]), "+v"(wi1B[14]), "+v"(wi1B[15]));
        asm volatile("" : "+v"(wh1A[0]), "+v"(wh1A[1]), "+v"(wh1A[2]), "+v"(wh1A[3]),
                          "+v"(wh1A[4]), "+v"(wh1A[5]), "+v"(wh1A[6]), "+v"(wh1A[7]),
                          "+v"(wh1A[8]), "+v"(wh1A[9]), "+v"(wh1A[10]), "+v"(wh1A[11]),
                          "+v"(wh1A[12]), "+v"(wh1A[13]), "+v"(wh1A[14]), "+v"(wh1A[15]));
        asm volatile("" : "+v"(wh1B[0]), "+v"(wh1B[1]), "+v"(wh1B[2]), "+v"(wh1B[3]),
                          "+v"(wh1B[4]), "+v"(wh1B[5]), "+v"(wh1B[6]), "+v"(wh1B[7]),
                          "+v"(wh1B[8]), "+v"(wh1B[9]), "+v"(wh1B[10]), "+v"(wh1B[11]),
                          "+v"(wh1B[12]), "+v"(wh1B[13]), "+v"(wh1B[14]), "+v"(wh1B[15]));
        asm volatile("" : "+v"(wlc[0]), "+v"(wlc[1]), "+v"(wlc[2]), "+v"(wlc[3]),
                          "+v"(wlc[4]), "+v"(wlc[5]), "+v"(wlc[6]), "+v"(wlc[7]),
                          "+v"(wlc[8]), "+v"(wlc[9]), "+v"(wlc[10]), "+v"(wlc[11]),
                          "+v"(wlc[12]), "+v"(wlc[13]), "+v"(wlc[14]), "+v"(wlc[15]));
        asm volatile("" : "+v"(wctA), "+v"(wctB));
    }
}

// ---------------- Fallback (R3-style, used only if ws too small) ----------
extern "C" __global__ void __launch_bounds__(128, 2)
lstm_opt_enc(const float* __restrict__ states, const float* __restrict__ taup,
             const float* __restrict__ gumbel, const float* __restrict__ w_ih0,
             const float* __restrict__ w_hh0, const float* __restrict__ b_ih0,
             const float* __restrict__ b_hh0, const float* __restrict__ w_ih1,
             const float* __restrict__ w_hh1, const float* __restrict__ b_ih1,
             const float* __restrict__ b_hh1, const float* __restrict__ w_lin,
             const float* __restrict__ b_lin, float* __restrict__ out)
{
    const int b   = blockIdx.x;
    const int tid = threadIdx.x;
    const int l   = tid & 63;
    const int u0  = l & 15;
    const int g   = l >> 4;
    const int wv  = tid >> 6;
    const int u   = wv * 16 + u0;
    const int r   = g * 32 + u;

    __shared__ __align__(16) float xb[2][DD];
    __shared__ __align__(16) float h1b[2][HH];
    __shared__ __align__(16) float h2b[2][HH];

    float wi0r[68], wh0r[HH], wi1r[HH], wh1r[HH];
#pragma unroll
    for (int k = 0; k < 68; ++k) wi0r[k] = w_ih0[r * 68 + k];
#pragma unroll
    for (int k = 0; k < HH; ++k) wh0r[k] = w_hh0[r * HH + k];
#pragma unroll
    for (int k = 0; k < HH; ++k) wi1r[k] = w_ih1[r * HH + k];
#pragma unroll
    for (int k = 0; k < HH; ++k) wh1r[k] = w_hh1[r * HH + k];
    const float bias0 = b_ih0[r] + b_hh0[r];
    const float bias1 = b_ih1[r] + b_hh1[r];
    const float inv_tau = rcpf(taup[0]);
    const float wl0 = w_lin[g * HH + u0];
    const float wl1 = w_lin[g * HH + u0 + 16];
    const float blc = b_lin[g];

    float cst1 = 0.f, cst2 = 0.f;
    float y0 = 1.f, y1 = 0.f, y2 = 0.f, y3 = 0.f;

    const float* __restrict__ sb = states + (size_t)b * TT * DD;
    float* __restrict__ ob = out + (size_t)b * TT * CC;

    float xr = 0.f;
    if (tid < DD) xr = sb[tid];
    if (tid < HH) { h1b[0][tid] = 0.f; h2b[0][tid] = 0.f; }
    if (tid < DD) { xb[0][tid] = xr; xr = sb[DD + tid]; }
    __syncthreads();

    for (int t = 0; t < TT; ++t) {
        const int p = t & 1, np = p ^ 1;
        if (tid < DD) { xb[np][tid] = xr; }
        const int tn = (t + 2 < TT) ? t + 2 : TT - 1;
        if (tid < DD) { xr = sb[tn * DD + tid]; }
        const float4 gt = *(const float4*)(gumbel + ((size_t)t * BB + b) * CC);

        float a0 = bias0, a1 = 0.f, a2 = 0.f, a3 = 0.f;
        const float4* xv = (const float4*)xb[p];
#pragma unroll
        for (int k = 0; k < 16; ++k) {
            float4 x4 = xv[k];
            a0 = fmaf(wi0r[4 * k + 0], x4.x, a0);
            a1 = fmaf(wi0r[4 * k + 1], x4.y, a1);
            a2 = fmaf(wi0r[4 * k + 2], x4.z, a2);
            a3 = fmaf(wi0r[4 * k + 3], x4.w, a3);
        }
        a0 = fmaf(wi0r[64], y0, a0);
        a1 = fmaf(wi0r[65], y1, a1);
        a2 = fmaf(wi0r[66], y2, a2);
        a3 = fmaf(wi0r[67], y3, a3);
        const float4* h1v = (const float4*)h1b[p];
#pragma unroll
        for (int k = 0; k < 8; ++k) {
            float4 h4 = h1v[k];
            a0 = fmaf(wh0r[4 * k + 0], h4.x, a0);
            a1 = fmaf(wh0r[4 * k + 1], h4.y, a1);
            a2 = fmaf(wh0r[4 * k + 2], h4.z, a2);
            a3 = fmaf(wh0r[4 * k + 3], h4.w, a3);
        }
        float z = (a0 + a1) + (a2 + a3);
        float v1  = __shfl_xor(z, 16, 64);
        float lo  = (g & 1) ? v1 : z;
        float hi  = (g & 1) ? z  : v1;
        float lo2 = __shfl_xor(lo, 32, 64);
        float hi2 = __shfl_xor(hi, 32, 64);
        float zi = (g < 2) ? lo  : lo2;
        float zf = (g < 2) ? hi  : hi2;
        float zg = (g < 2) ? lo2 : lo;
        float zo = (g < 2) ? hi2 : hi;
        float sf = rcpf(1.0f + __expf(-zf));
        float si = rcpf(1.0f + __expf(-zi));
        float tg = 1.0f - 2.0f * rcpf(__expf(2.0f * zg) + 1.0f);
        float so = rcpf(1.0f + __expf(-zo));
        cst1 = sf * cst1 + si * tg;
        float h1new = so * (1.0f - 2.0f * rcpf(__expf(2.0f * cst1) + 1.0f));
        if (g == 0) h1b[np][u] = h1new;
        __syncthreads();

        a0 = bias1; a1 = 0.f; a2 = 0.f; a3 = 0.f;
        const float4* h1n = (const float4*)h1b[np];
        const float4* h2v = (const float4*)h2b[p];
#pragma unroll
        for (int k = 0; k < 8; ++k) {
            float4 h4 = h1n[k];
            float4 g4 = h2v[k];
            a0 = fmaf(wi1r[4 * k + 0], h4.x, a0);
            a1 = fmaf(wi1r[4 * k + 1], h4.y, a1);
            a2 = fmaf(wi1r[4 * k + 2], h4.z, a2);
            a3 = fmaf(wi1r[4 * k + 3], h4.w, a3);
            a0 = fmaf(wh1r[4 * k + 0], g4.x, a0);
            a1 = fmaf(wh1r[4 * k + 1], g4.y, a1);
            a2 = fmaf(wh1r[4 * k + 2], g4.z, a2);
            a3 = fmaf(wh1r[4 * k + 3], g4.w, a3);
        }
        z = (a0 + a1) + (a2 + a3);
        v1  = __shfl_xor(z, 16, 64);
        lo  = (g & 1) ? v1 : z;
        hi  = (g & 1) ? z  : v1;
        lo2 = __shfl_xor(lo, 32, 64);
        hi2 = __shfl_xor(hi, 32, 64);
        zi = (g < 2) ? lo  : lo2;
        zf = (g < 2) ? hi  : hi2;
        zg = (g < 2) ? lo2 : lo;
        zo = (g < 2) ? hi2 : hi;
        sf = rcpf(1.0f + __expf(-zf));
        si = rcpf(1.0f + __expf(-zi));
        tg = 1.0f - 2.0f * rcpf(__expf(2.0f * zg) + 1.0f);
        so = rcpf(1.0f + __expf(-zo));
        cst2 = sf * cst2 + si * tg;
        float h2new = so * (1.0f - 2.0f * rcpf(__expf(2.0f * cst2) + 1.0f));
        if (g == 0) h2b[np][u] = h2new;
        __syncthreads();

        float part = wl0 * h2b[np][u0] + wl1 * h2b[np][u0 + 16];
        part += __shfl_xor(part, 1, 64);
        part += __shfl_xor(part, 2, 64);
        part += __shfl_xor(part, 4, 64);
        part += __shfl_xor(part, 8, 64);
        float qown = part + blc;
        float t1 = __shfl_xor(qown, 16, 64);
        float t2 = __shfl_xor(qown, 32, 64);
        float t3 = __shfl_xor(t1, 32, 64);
        float q0 = (g == 0) ? qown : (g == 1) ? t1 : (g == 2) ? t2 : t3;
        float q1 = (g == 0) ? t1 : (g == 1) ? qown : (g == 2) ? t3 : t2;
        float q2 = (g == 0) ? t2 : (g == 1) ? t3 : (g == 2) ? qown : t1;
        float q3 = (g == 0) ? t3 : (g == 1) ? t2 : (g == 2) ? t1 : qown;
        float l0  = (q0 + gt.x) * inv_tau;
        float l1_ = (q1 + gt.y) * inv_tau;
        float l2  = (q2 + gt.z) * inv_tau;
        float l3  = (q3 + gt.w) * inv_tau;
        float m = fmaxf(fmaxf(l0, l1_), fmaxf(l2, l3));
        float e0 = __expf(l0 - m), e1 = __expf(l1_ - m);
        float e2 = __expf(l2 - m), e3 = __expf(l3 - m);
        float inv = rcpf((e0 + e1) + (e2 + e3));
        y0 = e0 * inv; y1 = e1 * inv; y2 = e2 * inv; y3 = e3 * inv;

        if (tid == 0) *(float4*)(ob + (size_t)t * CC) = make_float4(y0, y1, y2, y3);
    }
}

extern "C" void kernel_launch(void* const* d_in, const int* in_sizes, int n_in,
                              void* d_out, int out_size, void* d_ws, size_t ws_size,
                              hipStream_t stream) {
    const float* states = (const float*)d_in[0];
    const float* tau    = (const float*)d_in[1];
    const float* gumbel = (const float*)d_in[2];
    const float* w_ih0  = (const float*)d_in[3];
    const float* w_hh0  = (const float*)d_in[4];
    const float* b_ih0  = (const float*)d_in[5];
    const float* b_hh0  = (const float*)d_in[6];
    const float* w_ih1  = (const float*)d_in[7];
    const float* w_hh1  = (const float*)d_in[8];
    const float* b_ih1  = (const float*)d_in[9];
    const float* b_hh1  = (const float*)d_in[10];
    const float* w_lin  = (const float*)d_in[11];
    const float* b_lin  = (const float*)d_in[12];
    float* out = (float*)d_out;

    const size_t zx_bytes = (size_t)BB * TT * 128 * 4;
    if (ws_size >= zx_bytes) {
        float* zx = (float*)d_ws;
        hipLaunchKernelGGL(zx_gemm, dim3(TT / 16, BB), dim3(128), 0, stream,
                           states, w_ih0, b_ih0, b_hh0, zx);
        hipLaunchKernelGGL(lstm_pipe2, dim3(BB / 2), dim3(64), 0, stream,
                           zx, tau, gumbel, w_ih0, w_hh0, w_ih1, w_hh1,
                           b_ih1, b_hh1, w_lin, b_lin, out);
    } else {
        hipLaunchKernelGGL(lstm_opt_enc, dim3(BB), dim3(128), 0, stream,
                           states, tau, gumbel, w_ih0, w_hh0, b_ih0, b_hh0,
                           w_ih1, w_hh1, b_ih1, b_hh1, w_lin, b_lin, out);
    }
}

// Round 18
// 925.942 us; speedup vs baseline: 1.6034x; 1.6034x over previous
//
#include <hip/hip_runtime.h>

#define BB 512
#define TT 1024
#define DD 64
#define HH 32
#define CC 4
#define TILE 16
#define NT (TT / TILE)

typedef float f4 __attribute__((ext_vector_type(4)));
typedef _Float16 hv2 __attribute__((ext_vector_type(2)));

#define LOG2E 1.4426950408889634f
#define TWO_LOG2E 2.8853900817779268f

__device__ __forceinline__ float rcpf(float x) { return __builtin_amdgcn_rcpf(x); }
__device__ __forceinline__ float ex2(float x) { return __builtin_amdgcn_exp2f(x); }
// prescaled-domain activations: input x = z * log2e
__device__ __forceinline__ float sigm2(float x) { return rcpf(1.0f + ex2(-x)); }
__device__ __forceinline__ float tanh2(float x) {
    return 1.0f - 2.0f * rcpf(ex2(x + x) + 1.0f);
}
// tanh of an UNSCALED value (cell state)
__device__ __forceinline__ float tanh_c(float c) {
    return 1.0f - 2.0f * rcpf(ex2(c * TWO_LOG2E) + 1.0f);
}
__device__ __forceinline__ float pk2(float a, float b) {
    hv2 t; t.x = (_Float16)a; t.y = (_Float16)b;
    return __builtin_bit_cast(float, t);
}
__device__ __forceinline__ hv2 bch(float x) { return __builtin_bit_cast(hv2, x); }
__device__ __forceinline__ float fdot2(float w, float h, float c) {
    return __builtin_amdgcn_fdot2(bch(w), bch(h), c, false);
}

// dot-32 via 16 v_dot2_f32_f16: W = float[16] (f16-pair bits), H4 = f4[4] raw f16x8
#define DOT32(a0, a1, a2, a3, W, H4)                    \
    _Pragma("unroll")                                   \
    for (int k2 = 0; k2 < 4; ++k2) {                    \
        f4 h_ = H4[k2];                                 \
        a0 = fdot2(W[4 * k2 + 0], h_.x, a0);            \
        a1 = fdot2(W[4 * k2 + 1], h_.y, a1);            \
        a2 = fdot2(W[4 * k2 + 2], h_.z, a2);            \
        a3 = fdot2(W[4 * k2 + 3], h_.w, a3);            \
    }

// gate combine via DS shuffle (R13-proven)
#define COMBINE(zA, zB, zi, zf, zg, zo)                 \
    {                                                   \
        float pA_ = __shfl_xor(zA, 32, 64);             \
        float pB_ = __shfl_xor(zB, 32, 64);             \
        zi = half ? pA_ : zA; zf = half ? zA : pA_;     \
        zg = half ? pB_ : zB; zo = half ? zB : pB_;     \
    }

// ---------------- Kernel 1: zx = (bias0 + w_ih0 . x) * log2e ----------------
__global__ void __launch_bounds__(128, 4)
zx_gemm(const float* __restrict__ states,  // [B,T,64]
        const float* __restrict__ w_ih0,   // [128,68]
        const float* __restrict__ b_ih0,
        const float* __restrict__ b_hh0,
        float* __restrict__ zx)            // [B,T,128] PRESCALED
{
    const int b = blockIdx.y;
    const int tile = blockIdx.x;
    const int tid = threadIdx.x;
    __shared__ __align__(16) float xs[16][DD];

    const int tbase = tile * 16;
#pragma unroll
    for (int i = 0; i < 2; ++i) {
        int f = i * 128 + tid;
        int row = f >> 4, c4 = f & 15;
        int t = tbase + row; if (t > TT - 1) t = TT - 1;
        ((f4*)xs)[f] = *(const f4*)(states + ((size_t)b * TT + t) * DD + c4 * 4);
    }
    __syncthreads();

    const int r = tid;
    const f4* wr = (const f4*)(w_ih0 + (size_t)r * 68);
    f4 w[16];
#pragma unroll
    for (int k = 0; k < 16; ++k) w[k] = wr[k];
    const float bias = b_ih0[r] + b_hh0[r];

    for (int i = 0; i < 16; ++i) {
        int t = tbase + i;
        if (t >= TT) break;
        const f4* xv = (const f4*)xs[i];
        float a0 = bias, a1 = 0.f, a2 = 0.f, a3 = 0.f;
#pragma unroll
        for (int k = 0; k < 16; ++k) {
            f4 x4 = xv[k];
            a0 = fmaf(w[k].x, x4.x, a0);
            a1 = fmaf(w[k].y, x4.y, a1);
            a2 = fmaf(w[k].z, x4.z, a2);
            a3 = fmaf(w[k].w, x4.w, a3);
        }
        zx[((size_t)b * TT + t) * 128 + r] = ((a0 + a1) + (a2 + a3)) * LOG2E;
    }
}

// ---------------- Kernel 2: R13 recurrence, spine-reordered ----------------
// Changes vs R13 (pure reordering, same numerics):
//  * q-dot issues BEFORE the L0 main dot: q's serial tail (perms->exp->rcp->
//    feedback) is the spine; L0's 64-fdot2 issue stream now hides it.
//  * t3 = shfl_xor(qown,48) directly: t1/t2/t3 all parallel (was 2 serial hops).
__global__ void __launch_bounds__(64, 1)
lstm_pipe(const float* __restrict__ zx,      // [B,TT,128] prescaled
          const float* __restrict__ taup,
          const float* __restrict__ gumbel,  // [T,B,1,C]
          const float* __restrict__ w_ih0,   // [128,68] (ct cols 64..67)
          const float* __restrict__ w_hh0,   // [128,32]
          const float* __restrict__ w_ih1,   // [128,32]
          const float* __restrict__ w_hh1,   // [128,32]
          const float* __restrict__ b_ih1,
          const float* __restrict__ b_hh1,
          const float* __restrict__ w_lin,   // [4,32]
          const float* __restrict__ b_lin,   // [4]
          float* __restrict__ out)           // [B,T,4]
{
    const int b    = blockIdx.x;
    const int l    = threadIdx.x;     // 0..63
    const int half = l >> 5;
    const int rA   = l;               // rows l (i|f) and l+64 (g|o)
    const int rB   = l + 64;
    const int c    = l >> 4;          // q channel group

    __shared__ __align__(16) float zbuf[2][TILE][128];   // 16 KB, +1-shifted rows
    __shared__ __align__(16) float4 gbuf[2][TILE];       // pre-scaled gumbel
    __shared__ __align__(16) _Float16 h1h[HH];
    __shared__ __align__(16) _Float16 h2h[HH];

    const float inv_tau = rcpf(taup[0]);
    const float gs = LOG2E * inv_tau;

    // ---- weights: wct f32*log2e; recurrent f16-pairs *log2e; wlc *gs ----
    f4 wctA = *(const f4*)(w_ih0 + (size_t)rA * 68 + 64);
    f4 wctB = *(const f4*)(w_ih0 + (size_t)rB * 68 + 64);
    wctA *= LOG2E; wctB *= LOG2E;
    float wh0A[16], wh0B[16], wi1A[16], wi1B[16], wh1A[16], wh1B[16], wlc[16];
#pragma unroll
    for (int k = 0; k < 8; ++k) {
        f4 w;
        w = *(const f4*)(w_hh0 + (size_t)rA * HH + 4 * k) * LOG2E;
        wh0A[2 * k] = pk2(w.x, w.y); wh0A[2 * k + 1] = pk2(w.z, w.w);
        w = *(const f4*)(w_hh0 + (size_t)rB * HH + 4 * k) * LOG2E;
        wh0B[2 * k] = pk2(w.x, w.y); wh0B[2 * k + 1] = pk2(w.z, w.w);
        w = *(const f4*)(w_ih1 + (size_t)rA * HH + 4 * k) * LOG2E;
        wi1A[2 * k] = pk2(w.x, w.y); wi1A[2 * k + 1] = pk2(w.z, w.w);
        w = *(const f4*)(w_ih1 + (size_t)rB * HH + 4 * k) * LOG2E;
        wi1B[2 * k] = pk2(w.x, w.y); wi1B[2 * k + 1] = pk2(w.z, w.w);
        w = *(const f4*)(w_hh1 + (size_t)rA * HH + 4 * k) * LOG2E;
        wh1A[2 * k] = pk2(w.x, w.y); wh1A[2 * k + 1] = pk2(w.z, w.w);
        w = *(const f4*)(w_hh1 + (size_t)rB * HH + 4 * k) * LOG2E;
        wh1B[2 * k] = pk2(w.x, w.y); wh1B[2 * k + 1] = pk2(w.z, w.w);
        w = *(const f4*)(w_lin + (size_t)c * HH + 4 * k) * gs;
        wlc[2 * k] = pk2(w.x, w.y); wlc[2 * k + 1] = pk2(w.z, w.w);
    }
    const float bias1A = (b_ih1[rA] + b_hh1[rA]) * LOG2E;
    const float bias1B = (b_ih1[rB] + b_hh1[rB]) * LOG2E;
    const float blc = b_lin[c] * gs;

    const float* __restrict__ zb = zx + (size_t)b * TT * 128;
    float* __restrict__ ob = out + (size_t)b * TT * CC;
    const int srow = l >> 5;          // staging: f4 slot f=i*64+l -> row i*2+srow, col4 l&31
    const int scol = l & 31;

    // ---- stage tile 0: zx rows 1..16, gumbel t=0..15 (scaled by gs) ----
    {
        f4 sz[8];
#pragma unroll
        for (int i = 0; i < 8; ++i) {
            int row = 1 + i * 2 + srow;
            sz[i] = *(const f4*)(zb + (size_t)row * 128 + scol * 4);
        }
        float4 gv = *(const float4*)(gumbel + ((size_t)(l & 15) * BB + b) * CC);
        gv.x *= gs; gv.y *= gs; gv.z *= gs; gv.w *= gs;
#pragma unroll
        for (int i = 0; i < 8; ++i) ((f4*)&zbuf[0][0][0])[i * 64 + l] = sz[i];
        if (l < 16) gbuf[0][l] = gv;
    }

    float cst1 = 0.f, cst2 = 0.f;
    f4 h1g[4];

    // ---- prologue: h1(0), h2(0); zx/wct prescaled; ct0 = one-hot(0) ----
    {
        float zA = zb[rA] + wctA.x;
        float zB = zb[rB] + wctB.x;
        float zi, zf, zg, zo;
        COMBINE(zA, zB, zi, zf, zg, zo);
        (void)zf;
        cst1 = sigm2(zi) * tanh2(zg);          // sigm(zf)*0 dropped (exact)
        float h1n = sigm2(zo) * tanh_c(cst1);
        if (l < HH) h1h[l] = (_Float16)h1n;
#pragma unroll
        for (int k2 = 0; k2 < 4; ++k2) h1g[k2] = ((const f4*)h1h)[k2];

        float bA0 = bias1A, bA1 = 0.f, bA2 = 0.f, bA3 = 0.f;
        float bB0 = bias1B, bB1 = 0.f, bB2 = 0.f, bB3 = 0.f;
        DOT32(bA0, bA1, bA2, bA3, wi1A, h1g);
        DOT32(bB0, bB1, bB2, bB3, wi1B, h1g);
        zA = (bA0 + bA1) + (bA2 + bA3);
        zB = (bB0 + bB1) + (bB2 + bB3);
        COMBINE(zA, zB, zi, zf, zg, zo);
        cst2 = sigm2(zi) * tanh2(zg);
        float h2n = sigm2(zo) * tanh_c(cst2);
        if (l < HH) h2h[l] = (_Float16)h2n;
    }

    // ---- main loop: tiles of 16 steps, staging split in 8-step halves ----
    for (int k = 0; k < NT; ++k) {
        const int cb = k & 1, nb = cb ^ 1;
        const int kn = (k + 1 < NT) ? k + 1 : 0;   // harmless reload at the end
        float4 gv;

#pragma unroll
        for (int hf = 0; hf < 2; ++hf) {
            // issue staging loads for next-tile rows hf*8 .. hf*8+7 (4 f4/lane)
            f4 szh[4];
#pragma unroll
            for (int i = 0; i < 4; ++i) {
                int ii = hf * 4 + i;
                int row = kn * TILE + 1 + ii * 2 + srow;
                if (row > TT - 1) row = TT - 1;
                szh[i] = *(const f4*)(zb + (size_t)row * 128 + scol * 4);
            }
            if (hf == 0)
                gv = *(const float4*)(gumbel +
                        ((size_t)(kn * TILE + (l & 15)) * BB + b) * CC);

#pragma unroll 2
            for (int s8 = 0; s8 < 8; ++s8) {
                const int s = hf * 8 + s8;
                const int t = k * TILE + s;

                // (1) early LDS issues: zx(t+1), gumbel(t), h2(t) allgather
                const float zxnA = zbuf[cb][s][rA];
                const float zxnB = zbuf[cb][s][rB];
                const float4 gtc = gbuf[cb][s];        // pre-scaled
                f4 h2g[4];
#pragma unroll
                for (int k2 = 0; k2 < 4; ++k2) h2g[k2] = ((const f4*)h2h)[k2];

                // (2) q'(t) FIRST: its serial tail is the spine
                float s0 = blc, s1 = 0.f, s2 = 0.f, s3 = 0.f;
                DOT32(s0, s1, s2, s3, wlc, h2g);
                float qown = (s0 + s1) + (s2 + s3);

                // (3) q perms: t1/t2/t3 all PARALLEL single-hop shuffles
                float t1 = __shfl_xor(qown, 16, 64);
                float t2 = __shfl_xor(qown, 32, 64);
                float t3 = __shfl_xor(qown, 48, 64);

                // (4) L0(t+1) main dot issues here; its stream hides the
                //     shuffle/exp latency of the q tail
                float aA0 = 0.f, aA1 = 0.f, aA2 = 0.f, aA3 = 0.f;
                float aB0 = 0.f, aB1 = 0.f, aB2 = 0.f, aB3 = 0.f;
                DOT32(aA0, aA1, aA2, aA3, wh0A, h1g);
                DOT32(aB0, aB1, aB2, aB3, wh0B, h1g);

                // (5) exp2 softmax (no max-sub, bounded); norm folded into feedback
                float q0 = (c == 0) ? qown : (c == 1) ? t1 : (c == 2) ? t2 : t3;
                float q1 = (c == 0) ? t1 : (c == 1) ? qown : (c == 2) ? t3 : t2;
                float q2 = (c == 0) ? t2 : (c == 1) ? t3 : (c == 2) ? qown : t1;
                float q3 = (c == 0) ? t3 : (c == 1) ? t2 : (c == 2) ? t1 : qown;
                float e0 = ex2(q0 + gtc.x);
                float e1 = ex2(q1 + gtc.y);
                float e2 = ex2(q2 + gtc.z);
                float e3 = ex2(q3 + gtc.w);
                float inv = rcpf((e0 + e1) + (e2 + e3));
                if (l == 0)
                    *(float4*)(ob + (size_t)t * CC) =
                        make_float4(e0 * inv, e1 * inv, e2 * inv, e3 * inv);

                // (6) L0 tail: + zx'(t+1) + (wct.e)*inv; combine; act -> h1(t+1)
                float weA0 = wctA.x * e0, weA1 = wctA.y * e1;
                float weA2 = wctA.z * e2, weA3 = wctA.w * e3;
                float weB0 = wctB.x * e0, weB1 = wctB.y * e1;
                float weB2 = wctB.z * e2, weB3 = wctB.w * e3;
                aA0 = fmaf(weA0, inv, aA0 + zxnA); aA1 = fmaf(weA1, inv, aA1);
                aA2 = fmaf(weA2, inv, aA2);        aA3 = fmaf(weA3, inv, aA3);
                aB0 = fmaf(weB0, inv, aB0 + zxnB); aB1 = fmaf(weB1, inv, aB1);
                aB2 = fmaf(weB2, inv, aB2);        aB3 = fmaf(weB3, inv, aB3);
                float zA = (aA0 + aA1) + (aA2 + aA3);
                float zB = (aB0 + aB1) + (aB2 + aB3);
                float zi, zf, zg, zo;
                COMBINE(zA, zB, zi, zf, zg, zo);
                cst1 = fmaf(sigm2(zf), cst1, sigm2(zi) * tanh2(zg));
                float h1n = sigm2(zo) * tanh_c(cst1);
                if (l < HH) h1h[l] = (_Float16)h1n;

                // (7) h1(t+1) allgather (hidden by (8)'s wh1 dot)
#pragma unroll
                for (int k2 = 0; k2 < 4; ++k2) h1g[k2] = ((const f4*)h1h)[k2];

                // (8) L1(t+1): wh1 . h2(t), then wi1 . h1(t+1)
                float bA0 = bias1A, bA1 = 0.f, bA2 = 0.f, bA3 = 0.f;
                float bB0 = bias1B, bB1 = 0.f, bB2 = 0.f, bB3 = 0.f;
                DOT32(bA0, bA1, bA2, bA3, wh1A, h2g);
                DOT32(bB0, bB1, bB2, bB3, wh1B, h2g);
                DOT32(bA0, bA1, bA2, bA3, wi1A, h1g);
                DOT32(bB0, bB1, bB2, bB3, wi1B, h1g);
                zA = (bA0 + bA1) + (bA2 + bA3);
                zB = (bB0 + bB1) + (bB2 + bB3);
                COMBINE(zA, zB, zi, zf, zg, zo);
                cst2 = fmaf(sigm2(zf), cst2, sigm2(zi) * tanh2(zg));
                float h2n = sigm2(zo) * tanh_c(cst2);
                if (l < HH) h2h[l] = (_Float16)h2n;
            }

            // commit this half's staged rows (>=8 steps of vmcnt slack)
#pragma unroll
            for (int i = 0; i < 4; ++i)
                ((f4*)&zbuf[nb][0][0])[(hf * 4 + i) * 64 + l] = szh[i];
        }
        gv.x *= gs; gv.y *= gs; gv.z *= gs; gv.w *= gs;
        if (l < 16) gbuf[nb][l] = gv;

        // ---- weight pins ONCE PER TILE ----
        asm volatile("" : "+v"(wh0A[0]), "+v"(wh0A[1]), "+v"(wh0A[2]), "+v"(wh0A[3]),
                          "+v"(wh0A[4]), "+v"(wh0A[5]), "+v"(wh0A[6]), "+v"(wh0A[7]),
                          "+v"(wh0A[8]), "+v"(wh0A[9]), "+v"(wh0A[10]), "+v"(wh0A[11]),
                          "+v"(wh0A[12]), "+v"(wh0A[13]), "+v"(wh0A[14]), "+v"(wh0A[15]));
        asm volatile("" : "+v"(wh0B[0]), "+v"(wh0B[1]), "+v"(wh0B[2]), "+v"(wh0B[3]),
                          "+v"(wh0B[4]), "+v"(wh0B[5]), "+v"(wh0B[6]), "+v"(wh0B[7]),
                          "+v"(wh0B[8]), "+v"(wh0B[9]), "+v"(wh0B[10]), "+v"(wh0B[11]),
                          "+v"(wh0B[12]), "+v"(wh0B[13]), "+v"(wh0B[14]), "+v"(wh0B[15]));
        asm volatile("" : "+v"(wi1A[0]), "+v"(wi1A[1]), "+v"(wi1A[2]), "+v"(wi1A[3]),
                          "+v"(wi1A[4]), "+v"(wi1A[5]), "+v"(wi1A[6]), "+v"(wi1A[7]),
                          "+v"(wi1A[8]), "+v"(wi1A[9]), "+v"(wi1A[10]), "+v"(wi1A[11]),
                          "+v"(wi1A[12]), "+v"(wi1A[13]), "+v"(wi1A[14]), "+v"(wi1A[15]));
        asm volatile("" : "+v"(wi1B[0]), "+v"(wi1B[1]), "+v"(wi1B[2]), "+v"(wi1B[3]),
                          "+v"(wi1B[4]), "+v"(wi1B[5]), "+v"(wi1B[6]), "+v"(wi1B[7]),
                          "+v"(wi1B[8]), "+v"(wi1B[9]), "+v"(wi1B[10]), "+v"(wi1B[11]),
                          "+v"(wi1B[12]), "+v"(wi1B[13]), "+v"(wi1B[14]), "+v"(wi1B[15]));
        asm volatile("" : "+v"(wh1A[0]), "+v"(wh1A[1]), "+v"(wh1A[2]), "+v"(wh1A[3]),
                          "+v"(wh1A[4]), "+v"(wh1A[5]), "+v"(wh1A[6]), "+v"(wh1A[7]),
                          "+v"(wh1A[8]), "+v"(wh1A[9]), "+v"(wh1A[10]), "+v"(wh1A[11]),
                          "+v"(wh1A[12]), "+v"(wh1A[13]), "+v"(wh1A[14]), "+v"(wh1A[15]));
        asm volatile("" : "+v"(wh1B[0]), "+v"(wh1B[1]), "+v"(wh1B[2]), "+v"(wh1B[3]),
                          "+v"(wh1B[4]), "+v"(wh1B[5]), "+v"(wh1B[6]), "+v"(wh1B[7]),
                          "+v"(wh1B[8]), "+v"(wh1B[9]), "+v"(wh1B[10]), "+v"(wh1B[11]),
                          "+v"(wh1B[12]), "+v"(wh1B[13]), "+v"(wh1B[14]), "+v"(wh1B[15]));
        asm volatile("" : "+v"(wlc[0]), "+v"(wlc[1]), "+v"(wlc[2]), "+v"(wlc[3]),
                          "+v"(wlc[4]), "+v"(wlc[5]), "+v"(wlc[6]), "+v"(wlc[7]),
                          "+v"(wlc[8]), "+v"(wlc[9]), "+v"(wlc[10]), "+v"(wlc[11]),
                          "+v"(wlc[12]), "+v"(wlc[13]), "+v"(wlc[14]), "+v"(wlc[15]));
        asm volatile("" : "+v"(wctA), "+v"(wctB));
    }
}

// ---------------- Fallback (R3-style, used only if ws too small) ----------
extern "C" __global__ void __launch_bounds__(128, 2)
lstm_opt_enc(const float* __restrict__ states, const float* __restrict__ taup,
             const float* __restrict__ gumbel, const float* __restrict__ w_ih0,
             const float* __restrict__ w_hh0, const float* __restrict__ b_ih0,
             const float* __restrict__ b_hh0, const float* __restrict__ w_ih1,
             const float* __restrict__ w_hh1, const float* __restrict__ b_ih1,
             const float* __restrict__ b_hh1, const float* __restrict__ w_lin,
             const float* __restrict__ b_lin, float* __restrict__ out)
{
    const int b   = blockIdx.x;
    const int tid = threadIdx.x;
    const int l   = tid & 63;
    const int wv  = tid >> 6;
    const int u0  = l & 15;
    const int g   = l >> 4;
    const int u   = wv * 16 + u0;
    const int r   = g * 32 + u;

    __shared__ __align__(16) float xb[2][DD];
    __shared__ __align__(16) float h1b[2][HH];
    __shared__ __align__(16) float h2b[2][HH];

    float wi0r[68], wh0r[HH], wi1r[HH], wh1r[HH];
#pragma unroll
    for (int k = 0; k < 68; ++k) wi0r[k] = w_ih0[r * 68 + k];
#pragma unroll
    for (int k = 0; k < HH; ++k) wh0r[k] = w_hh0[r * HH + k];
#pragma unroll
    for (int k = 0; k < HH; ++k) wi1r[k] = w_ih1[r * HH + k];
#pragma unroll
    for (int k = 0; k < HH; ++k) wh1r[k] = w_hh1[r * HH + k];
    const float bias0 = b_ih0[r] + b_hh0[r];
    const float bias1 = b_ih1[r] + b_hh1[r];
    const float inv_tau = rcpf(taup[0]);
    const float wl0 = w_lin[g * HH + u0];
    const float wl1 = w_lin[g * HH + u0 + 16];
    const float blc = b_lin[g];

    float cst1 = 0.f, cst2 = 0.f;
    float y0 = 1.f, y1 = 0.f, y2 = 0.f, y3 = 0.f;

    const float* __restrict__ sb = states + (size_t)b * TT * DD;
    float* __restrict__ ob = out + (size_t)b * TT * CC;

    float xr = 0.f;
    if (tid < DD) xr = sb[tid];
    if (tid < HH) { h1b[0][tid] = 0.f; h2b[0][tid] = 0.f; }
    if (tid < DD) { xb[0][tid] = xr; xr = sb[DD + tid]; }
    __syncthreads();

    for (int t = 0; t < TT; ++t) {
        const int p = t & 1, np = p ^ 1;
        if (tid < DD) { xb[np][tid] = xr; }
        const int tn = (t + 2 < TT) ? t + 2 : TT - 1;
        if (tid < DD) { xr = sb[tn * DD + tid]; }
        const float4 gt = *(const float4*)(gumbel + ((size_t)t * BB + b) * CC);

        float a0 = bias0, a1 = 0.f, a2 = 0.f, a3 = 0.f;
        const float4* xv = (const float4*)xb[p];
#pragma unroll
        for (int k = 0; k < 16; ++k) {
            float4 x4 = xv[k];
            a0 = fmaf(wi0r[4 * k + 0], x4.x, a0);
            a1 = fmaf(wi0r[4 * k + 1], x4.y, a1);
            a2 = fmaf(wi0r[4 * k + 2], x4.z, a2);
            a3 = fmaf(wi0r[4 * k + 3], x4.w, a3);
        }
        a0 = fmaf(wi0r[64], y0, a0);
        a1 = fmaf(wi0r[65], y1, a1);
        a2 = fmaf(wi0r[66], y2, a2);
        a3 = fmaf(wi0r[67], y3, a3);
        const float4* h1v = (const float4*)h1b[p];
#pragma unroll
        for (int k = 0; k < 8; ++k) {
            float4 h4 = h1v[k];
            a0 = fmaf(wh0r[4 * k + 0], h4.x, a0);
            a1 = fmaf(wh0r[4 * k + 1], h4.y, a1);
            a2 = fmaf(wh0r[4 * k + 2], h4.z, a2);
            a3 = fmaf(wh0r[4 * k + 3], h4.w, a3);
        }
        float z = (a0 + a1) + (a2 + a3);
        float v1  = __shfl_xor(z, 16, 64);
        float lo  = (g & 1) ? v1 : z;
        float hi  = (g & 1) ? z  : v1;
        float lo2 = __shfl_xor(lo, 32, 64);
        float hi2 = __shfl_xor(hi, 32, 64);
        float zi = (g < 2) ? lo  : lo2;
        float zf = (g < 2) ? hi  : hi2;
        float zg = (g < 2) ? lo2 : lo;
        float zo = (g < 2) ? hi2 : hi;
        float sf = rcpf(1.0f + __expf(-zf));
        float si = rcpf(1.0f + __expf(-zi));
        float tg = 1.0f - 2.0f * rcpf(__expf(2.0f * zg) + 1.0f);
        float so = rcpf(1.0f + __expf(-zo));
        cst1 = sf * cst1 + si * tg;
        float h1new = so * (1.0f - 2.0f * rcpf(__expf(2.0f * cst1) + 1.0f));
        if (g == 0) h1b[np][u] = h1new;
        __syncthreads();

        a0 = bias1; a1 = 0.f; a2 = 0.f; a3 = 0.f;
        const float4* h1n = (const float4*)h1b[np];
        const float4* h2v = (const float4*)h2b[p];
#pragma unroll
        for (int k = 0; k < 8; ++k) {
            float4 h4 = h1n[k];
            float4 g4 = h2v[k];
            a0 = fmaf(wi1r[4 * k + 0], h4.x, a0);
            a1 = fmaf(wi1r[4 * k + 1], h4.y, a1);
            a2 = fmaf(wi1r[4 * k + 2], h4.z, a2);
            a3 = fmaf(wi1r[4 * k + 3], h4.w, a3);
            a0 = fmaf(wh1r[4 * k + 0], g4.x, a0);
            a1 = fmaf(wh1r[4 * k + 1], g4.y, a1);
            a2 = fmaf(wh1r[4 * k + 2], g4.z, a2);
            a3 = fmaf(wh1r[4 * k + 3], g4.w, a3);
        }
        z = (a0 + a1) + (a2 + a3);
        v1  = __shfl_xor(z, 16, 64);
        lo  = (g & 1) ? v1 : z;
        hi  = (g & 1) ? z  : v1;
        lo2 = __shfl_xor(lo, 32, 64);
        hi2 = __shfl_xor(hi, 32, 64);
        zi = (g < 2) ? lo  : lo2;
        zf = (g < 2) ? hi  : hi2;
        zg = (g < 2) ? lo2 : lo;
        zo = (g < 2) ? hi2 : hi;
        sf = rcpf(1.0f + __expf(-zf));
        si = rcpf(1.0f + __expf(-zi));
        tg = 1.0f - 2.0f * rcpf(__expf(2.0f * zg) + 1.0f);
        so = rcpf(1.0f + __expf(-zo));
        cst2 = sf * cst2 + si * tg;
        float h2new = so * (1.0f - 2.0f * rcpf(__expf(2.0f * cst2) + 1.0f));
        if (g == 0) h2b[np][u] = h2new;
        __syncthreads();

        float part = wl0 * h2b[np][u0] + wl1 * h2b[np][u0 + 16];
        part += __shfl_xor(part, 1, 64);
        part += __shfl_xor(part, 2, 64);
        part += __shfl_xor(part, 4, 64);
        part += __shfl_xor(part, 8, 64);
        float qown = part + blc;
        float t1 = __shfl_xor(qown, 16, 64);
        float t2 = __shfl_xor(qown, 32, 64);
        float t3 = __shfl_xor(t1, 32, 64);
        float q0 = (g == 0) ? qown : (g == 1) ? t1 : (g == 2) ? t2 : t3;
        float q1 = (g == 0) ? t1 : (g == 1) ? qown : (g == 2) ? t3 : t2;
        float q2 = (g == 0) ? t2 : (g == 1) ? t3 : (g == 2) ? qown : t1;
        float q3 = (g == 0) ? t3 : (g == 1) ? t2 : (g == 2) ? t1 : qown;
        float l0  = (q0 + gt.x) * inv_tau;
        float l1_ = (q1 + gt.y) * inv_tau;
        float l2  = (q2 + gt.z) * inv_tau;
        float l3  = (q3 + gt.w) * inv_tau;
        float m = fmaxf(fmaxf(l0, l1_), fmaxf(l2, l3));
        float e0 = __expf(l0 - m), e1 = __expf(l1_ - m);
        float e2 = __expf(l2 - m), e3 = __expf(l3 - m);
        float inv = rcpf((e0 + e1) + (e2 + e3));
        y0 = e0 * inv; y1 = e1 * inv; y2 = e2 * inv; y3 = e3 * inv;

        if (tid == 0) *(float4*)(ob + (size_t)t * CC) = make_float4(y0, y1, y2, y3);
    }
}

extern "C" void kernel_launch(void* const* d_in, const int* in_sizes, int n_in,
                              void* d_out, int out_size, void* d_ws, size_t ws_size,
                              hipStream_t stream) {
    const float* states = (const float*)d_in[0];
    const float* tau    = (const float*)d_in[1];
    const float* gumbel = (const float*)d_in[2];
    const float* w_ih0  = (const float*)d_in[3];
    const float* w_hh0  = (const float*)d_in[4];
    const float* b_ih0  = (const float*)d_in[5];
    const float* b_hh0  = (const float*)d_in[6];
    const float* w_ih1  = (const float*)d_in[7];
    const float* w_hh1  = (const float*)d_in[8];
    const float* b_ih1  = (const float*)d_in[9];
    const float* b_hh1  = (const float*)d_in[10];
    const float* w_lin  = (const float*)d_in[11];
    const float* b_lin  = (const float*)d_in[12];
    float* out = (float*)d_out;

    const size_t zx_bytes = (size_t)BB * TT * 128 * 4;
    if (ws_size >= zx_bytes) {
        float* zx = (float*)d_ws;
        hipLaunchKernelGGL(zx_gemm, dim3(TT / 16, BB), dim3(128), 0, stream,
                           states, w_ih0, b_ih0, b_hh0, zx);
        hipLaunchKernelGGL(lstm_pipe, dim3(BB), dim3(64), 0, stream,
                           zx, tau, gumbel, w_ih0, w_hh0, w_ih1, w_hh1,
                           b_ih1, b_hh1, w_lin, b_lin, out);
    } else {
        hipLaunchKernelGGL(lstm_opt_enc, dim3(BB), dim3(128), 0, stream,
                           states, tau, gumbel, w_ih0, w_hh0, b_ih0, b_hh0,
                           w_ih1, w_hh1, b_ih1, b_hh1, w_lin, b_lin, out);
    }
}